// Round 9
// baseline (882.578 us; speedup 1.0000x reference)
//
#include <hip/hip_runtime.h>
#include <hip/hip_bf16.h>
#include <math.h>

#define T_STEPS 2048
#define B_SZ 8
#define D_SZ 1024
#define M_SZ (T_STEPS * B_SZ)   // 16384 rows (t*B + b)
#define K_SZ D_SZ               // 1024
#define N_SZ (2 * D_SZ)         // 2048 (alpha cols | v cols)

#define BM 128
#define BN 128
#define BK 32

typedef __attribute__((ext_vector_type(8))) short bf16x8;
typedef __attribute__((ext_vector_type(4))) float f32x4;

__device__ __forceinline__ float sigmoidf_(float z) {
    return 1.0f / (1.0f + __expf(-z));
}

// round-to-nearest-even fp32 -> bf16, also returns the back-converted fp32
__device__ __forceinline__ ushort bf16_rne(float f, float* back) {
    uint u = __float_as_uint(f);
    uint r = (u + 0x7FFFu + ((u >> 16) & 1u)) >> 16;
    *back = __uint_as_float(r << 16);
    return (ushort)r;
}

// ---------------- conversion pre-pass: fp32 -> (hi, lo) bf16 arrays ----------
__global__ __launch_bounds__(256) void conv_split(
    const float* __restrict__ src,
    ushort* __restrict__ dh,
    ushort* __restrict__ dl,
    int n8)
{
    const int i = blockIdx.x * 256 + threadIdx.x;
    if (i >= n8) return;
    const size_t base = (size_t)i * 8;
    const float4 f0 = *reinterpret_cast<const float4*>(src + base);
    const float4 f1 = *reinterpret_cast<const float4*>(src + base + 4);
    const float f[8] = {f0.x, f0.y, f0.z, f0.w, f1.x, f1.y, f1.z, f1.w};
    ushort hi[8], lo[8];
    #pragma unroll
    for (int j = 0; j < 8; ++j) {
        float back;
        hi[j] = bf16_rne(f[j], &back);
        float dummy;
        lo[j] = bf16_rne(f[j] - back, &dummy);
    }
    *reinterpret_cast<uint4*>(dh + base) = *reinterpret_cast<const uint4*>(hi);
    *reinterpret_cast<uint4*>(dl + base) = *reinterpret_cast<const uint4*>(lo);
}

// ---------------- MFMA GEMM on pre-split bf16, XOR-swizzled LDS -------------
// LDS row = 64 ushort = 128 B = 8 chunks of 16 B. Chunks 0-3: hi k=0..31,
// chunks 4-7: lo k=0..31. Physical chunk = logical ^ (row & 7)  (bijective,
// spreads b128 reads across all 32 banks).
__global__ __launch_bounds__(256) void gemm_gates2(
    const ushort* __restrict__ xh, const ushort* __restrict__ xl,
    const ushort* __restrict__ Wah, const ushort* __restrict__ Wal,
    const ushort* __restrict__ Wvh, const ushort* __restrict__ Wvl,
    const float* __restrict__ ba, const float* __restrict__ bv,
    float* __restrict__ out)
{
    __shared__ ushort sA[BM * 64];
    __shared__ ushort sB[BN * 64];

    const int m0 = blockIdx.x * BM;
    const int n0 = blockIdx.y * BN;
    const bool is_v = (n0 >= D_SZ);
    const int n0l = is_v ? (n0 - D_SZ) : n0;
    const ushort* Bh = (is_v ? Wvh : Wah) + (size_t)n0l * K_SZ;
    const ushort* Bl = (is_v ? Wvl : Wal) + (size_t)n0l * K_SZ;

    const int tid = threadIdx.x;
    const int wid = tid >> 6;
    const int lane = tid & 63;
    const int wm = wid >> 1;
    const int wn = wid & 1;
    const int l15 = lane & 15;
    const int l4 = lane >> 4;

    // staging map: thread handles rows r0+32p (p=0..3), chunk c (16B)
    const int r0 = tid >> 3;     // 0..31
    const int c = tid & 7;       // 0..7  (c<4: hi chunk c; c>=4: lo chunk c-4)
    const int kc = (c & 3) * 8;  // k element offset within tile

    const ushort* Asrc = (c < 4) ? xh : xl;
    const ushort* Bsrc = (c < 4) ? Bh : Bl;

    f32x4 acc[4][4];
    #pragma unroll
    for (int i = 0; i < 4; ++i)
        #pragma unroll
        for (int j = 0; j < 4; ++j)
            acc[i][j] = (f32x4){0.f, 0.f, 0.f, 0.f};

    for (int k0 = 0; k0 < K_SZ; k0 += BK) {
        uint4 areg[4], breg[4];
        #pragma unroll
        for (int p = 0; p < 4; ++p) {
            areg[p] = *reinterpret_cast<const uint4*>(
                Asrc + (size_t)(m0 + r0 + 32 * p) * K_SZ + k0 + kc);
            breg[p] = *reinterpret_cast<const uint4*>(
                Bsrc + (size_t)(r0 + 32 * p) * K_SZ + k0 + kc);
        }

        __syncthreads();   // previous iteration's LDS reads complete

        #pragma unroll
        for (int p = 0; p < 4; ++p) {
            const int row = r0 + 32 * p;
            const int phys = c ^ (row & 7);
            *reinterpret_cast<uint4*>(&sA[row * 64 + phys * 8]) = areg[p];
            *reinterpret_cast<uint4*>(&sB[row * 64 + phys * 8]) = breg[p];
        }

        __syncthreads();

        bf16x8 ah[4], al[4];
        #pragma unroll
        for (int i = 0; i < 4; ++i) {
            const int r = wm * 64 + i * 16 + l15;
            const int ph = (l4) ^ (r & 7);
            const int pl = (4 + l4) ^ (r & 7);
            ah[i] = *reinterpret_cast<const bf16x8*>(&sA[r * 64 + ph * 8]);
            al[i] = *reinterpret_cast<const bf16x8*>(&sA[r * 64 + pl * 8]);
        }
        #pragma unroll
        for (int j = 0; j < 4; ++j) {
            const int cr = wn * 64 + j * 16 + l15;
            const int ph = (l4) ^ (cr & 7);
            const int pl = (4 + l4) ^ (cr & 7);
            const bf16x8 bh = *reinterpret_cast<const bf16x8*>(&sB[cr * 64 + ph * 8]);
            const bf16x8 bl = *reinterpret_cast<const bf16x8*>(&sB[cr * 64 + pl * 8]);
            #pragma unroll
            for (int i = 0; i < 4; ++i) {
                acc[i][j] = __builtin_amdgcn_mfma_f32_16x16x32_bf16(ah[i], bh, acc[i][j], 0, 0, 0);
                acc[i][j] = __builtin_amdgcn_mfma_f32_16x16x32_bf16(al[i], bh, acc[i][j], 0, 0, 0);
                acc[i][j] = __builtin_amdgcn_mfma_f32_16x16x32_bf16(ah[i], bl, acc[i][j], 0, 0, 0);
            }
        }
    }

    float* hbuf = out + (size_t)M_SZ * D_SZ;
    #pragma unroll
    for (int j = 0; j < 4; ++j) {
        const int n = n0 + wn * 64 + j * 16 + l15;
        const float bb = is_v ? bv[n - D_SZ] : ba[n];
        #pragma unroll
        for (int i = 0; i < 4; ++i) {
            const int mb = m0 + wm * 64 + i * 16 + l4 * 4;
            #pragma unroll
            for (int r = 0; r < 4; ++r) {
                const int m = mb + r;
                const float z = acc[i][j][r] + bb;
                if (!is_v) {
                    out[(size_t)m * D_SZ + n] = sigmoidf_(z);
                } else {
                    hbuf[(size_t)(m + B_SZ) * D_SZ + (n - D_SZ)] = z;
                }
            }
        }
    }
}

// ---------------- 3-kernel coalesced scan -----------------------------------
// grid (128 bd-groups, 64 chunks), wave = 64 consecutive bd lanes.
#define NCHUNK 64
#define CLEN (T_STEPS / NCHUNK)   // 32
#define STRIDE (B_SZ * D_SZ)      // 8192

__global__ __launch_bounds__(64) void scan_part(
    const float* __restrict__ out, float* __restrict__ P, float* __restrict__ Q)
{
    const int bd = blockIdx.x * 64 + threadIdx.x;
    const int chunk = blockIdx.y;
    const float* alpha = out;
    const float* hbuf = out + (size_t)M_SZ * D_SZ;

    float Pa = 1.f, q = 0.f;
    size_t idx = (size_t)(chunk * CLEN) * STRIDE + bd;
    #pragma unroll 4
    for (int s = 0; s < CLEN; ++s) {
        const float a = alpha[idx];
        const float v = hbuf[idx + STRIDE];
        q = fmaf(a, q, v);
        Pa *= a;
        idx += STRIDE;
    }
    P[(size_t)chunk * STRIDE + bd] = Pa;
    Q[(size_t)chunk * STRIDE + bd] = q;
}

__global__ __launch_bounds__(64) void scan_comb(
    float* __restrict__ out, const float* __restrict__ P,
    const float* __restrict__ Q, float* __restrict__ S)
{
    const int bd = blockIdx.x * 64 + threadIdx.x;
    float* hbuf = out + (size_t)M_SZ * D_SZ;
    float s = 0.f;
    #pragma unroll 8
    for (int c = 0; c < NCHUNK; ++c) {
        S[(size_t)c * STRIDE + bd] = s;
        s = fmaf(P[(size_t)c * STRIDE + bd], s, Q[(size_t)c * STRIDE + bd]);
    }
    hbuf[bd] = 0.f;   // h0
}

__global__ __launch_bounds__(64) void scan_final(
    float* __restrict__ out, const float* __restrict__ S)
{
    const int bd = blockIdx.x * 64 + threadIdx.x;
    const int chunk = blockIdx.y;
    float* alpha = out;
    float* hbuf = out + (size_t)M_SZ * D_SZ;

    float h = S[(size_t)chunk * STRIDE + bd];
    size_t idx = (size_t)(chunk * CLEN) * STRIDE + bd;
    #pragma unroll 4
    for (int s = 0; s < CLEN; ++s) {
        const float a = alpha[idx];
        const float v = hbuf[idx + STRIDE];
        h = fmaf(a, h, v);
        hbuf[idx + STRIDE] = h;
        alpha[idx] = h * h * sigmoidf_(h);
        idx += STRIDE;
    }
}

// ---------------- fallback (round-5) kernels --------------------------------
#define LDSS 40
__global__ __launch_bounds__(256) void gemm_gates_fb(
    const float* __restrict__ x,
    const float* __restrict__ Wa,
    const float* __restrict__ ba,
    const float* __restrict__ Wv,
    const float* __restrict__ bv,
    float* __restrict__ out)
{
    __shared__ ushort sAh[BM * LDSS];
    __shared__ ushort sAl[BM * LDSS];
    __shared__ ushort sBh[BN * LDSS];
    __shared__ ushort sBl[BN * LDSS];

    const int m0 = blockIdx.x * BM;
    const int n0 = blockIdx.y * BN;
    const bool is_v = (n0 >= D_SZ);
    const float* W = is_v ? (Wv + (size_t)(n0 - D_SZ) * K_SZ) : (Wa + (size_t)n0 * K_SZ);

    const int tid = threadIdx.x;
    const int wid = tid >> 6;
    const int lane = tid & 63;
    const int wm = wid >> 1;
    const int wn = wid & 1;
    const int l15 = lane & 15;
    const int l4 = lane >> 4;
    const int r0 = tid >> 3;
    const int c4 = tid & 7;

    const float* xp = x + (size_t)(m0 + r0) * K_SZ + c4 * 4;
    const float* wp = W + (size_t)r0 * K_SZ + c4 * 4;

    f32x4 acc[4][4];
    #pragma unroll
    for (int i = 0; i < 4; ++i)
        #pragma unroll
        for (int j = 0; j < 4; ++j)
            acc[i][j] = (f32x4){0.f, 0.f, 0.f, 0.f};

    for (int k0 = 0; k0 < K_SZ; k0 += BK) {
        float4 areg[4], breg[4];
        #pragma unroll
        for (int p = 0; p < 4; ++p) {
            areg[p] = *reinterpret_cast<const float4*>(xp + k0 + (size_t)(32 * p) * K_SZ);
            breg[p] = *reinterpret_cast<const float4*>(wp + k0 + (size_t)(32 * p) * K_SZ);
        }
        __syncthreads();
        #pragma unroll
        for (int p = 0; p < 4; ++p) {
            const int e = (r0 + 32 * p) * LDSS + c4 * 4;
            float bk;
            ushort4 hi, lo;
            float fa[4] = {areg[p].x, areg[p].y, areg[p].z, areg[p].w};
            hi.x = bf16_rne(fa[0], &bk); lo.x = bf16_rne(fa[0] - bk, &bk);
            hi.y = bf16_rne(fa[1], &bk); lo.y = bf16_rne(fa[1] - bk, &bk);
            hi.z = bf16_rne(fa[2], &bk); lo.z = bf16_rne(fa[2] - bk, &bk);
            hi.w = bf16_rne(fa[3], &bk); lo.w = bf16_rne(fa[3] - bk, &bk);
            *reinterpret_cast<ushort4*>(&sAh[e]) = hi;
            *reinterpret_cast<ushort4*>(&sAl[e]) = lo;
            float fb[4] = {breg[p].x, breg[p].y, breg[p].z, breg[p].w};
            hi.x = bf16_rne(fb[0], &bk); lo.x = bf16_rne(fb[0] - bk, &bk);
            hi.y = bf16_rne(fb[1], &bk); lo.y = bf16_rne(fb[1] - bk, &bk);
            hi.z = bf16_rne(fb[2], &bk); lo.z = bf16_rne(fb[2] - bk, &bk);
            hi.w = bf16_rne(fb[3], &bk); lo.w = bf16_rne(fb[3] - bk, &bk);
            *reinterpret_cast<ushort4*>(&sBh[e]) = hi;
            *reinterpret_cast<ushort4*>(&sBl[e]) = lo;
        }
        __syncthreads();

        bf16x8 ah[4], al[4];
        #pragma unroll
        for (int i = 0; i < 4; ++i) {
            const int r = wm * 64 + i * 16 + l15;
            ah[i] = *reinterpret_cast<const bf16x8*>(&sAh[r * LDSS + l4 * 8]);
            al[i] = *reinterpret_cast<const bf16x8*>(&sAl[r * LDSS + l4 * 8]);
        }
        #pragma unroll
        for (int j = 0; j < 4; ++j) {
            const int c = wn * 64 + j * 16 + l15;
            const bf16x8 bh = *reinterpret_cast<const bf16x8*>(&sBh[c * LDSS + l4 * 8]);
            const bf16x8 bl = *reinterpret_cast<const bf16x8*>(&sBl[c * LDSS + l4 * 8]);
            #pragma unroll
            for (int i = 0; i < 4; ++i) {
                acc[i][j] = __builtin_amdgcn_mfma_f32_16x16x32_bf16(ah[i], bh, acc[i][j], 0, 0, 0);
                acc[i][j] = __builtin_amdgcn_mfma_f32_16x16x32_bf16(al[i], bh, acc[i][j], 0, 0, 0);
                acc[i][j] = __builtin_amdgcn_mfma_f32_16x16x32_bf16(ah[i], bl, acc[i][j], 0, 0, 0);
            }
        }
    }

    float* hbuf = out + (size_t)M_SZ * D_SZ;
    #pragma unroll
    for (int j = 0; j < 4; ++j) {
        const int n = n0 + wn * 64 + j * 16 + l15;
        const float bb = is_v ? bv[n - D_SZ] : ba[n];
        #pragma unroll
        for (int i = 0; i < 4; ++i) {
            const int mb = m0 + wm * 64 + i * 16 + l4 * 4;
            #pragma unroll
            for (int r = 0; r < 4; ++r) {
                const int m = mb + r;
                const float z = acc[i][j][r] + bb;
                if (!is_v) {
                    out[(size_t)m * D_SZ + n] = sigmoidf_(z);
                } else {
                    hbuf[(size_t)(m + B_SZ) * D_SZ + (n - D_SZ)] = z;
                }
            }
        }
    }
}

#define SC_LANES 16
#define SC_CHUNKS 64
#define SC_LEN (T_STEPS / SC_CHUNKS)

__global__ __launch_bounds__(1024) void scan_hier(float* __restrict__ out)
{
    __shared__ float sP[SC_CHUNKS][SC_LANES];
    __shared__ float sQ[SC_CHUNKS][SC_LANES];
    __shared__ float sS[SC_CHUNKS][SC_LANES];

    float* alpha = out;
    float* hbuf = out + (size_t)M_SZ * D_SZ;
    const int tid = threadIdx.x;
    const int c = tid >> 4;
    const int l = tid & 15;
    const int bd = blockIdx.x * SC_LANES + l;
    const int t0 = c * SC_LEN;

    float P = 1.f, q = 0.f;
    {
        size_t idx = (size_t)t0 * STRIDE + bd;
        #pragma unroll 4
        for (int s = 0; s < SC_LEN; ++s) {
            const float a = alpha[idx];
            const float v = hbuf[idx + STRIDE];
            q = fmaf(a, q, v);
            P *= a;
            idx += STRIDE;
        }
    }
    sP[c][l] = P;
    sQ[c][l] = q;
    __syncthreads();

    if (tid < SC_LANES) {
        float s = 0.f;
        #pragma unroll 8
        for (int w = 0; w < SC_CHUNKS; ++w) {
            sS[w][tid] = s;
            s = fmaf(sP[w][tid], s, sQ[w][tid]);
        }
        hbuf[blockIdx.x * SC_LANES + tid] = 0.f;
    }
    __syncthreads();

    float h = sS[c][l];
    {
        size_t idx = (size_t)t0 * STRIDE + bd;
        #pragma unroll 4
        for (int s = 0; s < SC_LEN; ++s) {
            const float a = alpha[idx];
            const float v = hbuf[idx + STRIDE];
            h = fmaf(a, h, v);
            hbuf[idx + STRIDE] = h;
            alpha[idx] = h * h * sigmoidf_(h);
            idx += STRIDE;
        }
    }
}

// ---------------- launch ----------------------------------------------------
extern "C" void kernel_launch(void* const* d_in, const int* in_sizes, int n_in,
                              void* d_out, int out_size, void* d_ws, size_t ws_size,
                              hipStream_t stream) {
    const float* x  = (const float*)d_in[0];
    const float* Wa = (const float*)d_in[1];
    const float* ba = (const float*)d_in[2];
    const float* Wv = (const float*)d_in[3];
    const float* bv = (const float*)d_in[4];
    float* out = (float*)d_out;

    const size_t MB = 1024 * 1024;
    const size_t need = 78 * MB;

    if (ws_size >= need) {
        char* ws = (char*)d_ws;
        ushort* xh  = (ushort*)(ws);
        ushort* xl  = (ushort*)(ws + 32 * MB);
        ushort* Wah = (ushort*)(ws + 64 * MB);
        ushort* Wal = (ushort*)(ws + 66 * MB);
        ushort* Wvh = (ushort*)(ws + 68 * MB);
        ushort* Wvl = (ushort*)(ws + 70 * MB);
        float* P = (float*)(ws + 72 * MB);
        float* Q = (float*)(ws + 74 * MB);
        float* S = (float*)(ws + 76 * MB);

        conv_split<<<(M_SZ * K_SZ / 8 + 255) / 256, 256, 0, stream>>>(x, xh, xl, M_SZ * K_SZ / 8);
        conv_split<<<(D_SZ * K_SZ / 8 + 255) / 256, 256, 0, stream>>>(Wa, Wah, Wal, D_SZ * K_SZ / 8);
        conv_split<<<(D_SZ * K_SZ / 8 + 255) / 256, 256, 0, stream>>>(Wv, Wvh, Wvl, D_SZ * K_SZ / 8);

        dim3 grid(M_SZ / BM, N_SZ / BN);
        gemm_gates2<<<grid, 256, 0, stream>>>(xh, xl, Wah, Wal, Wvh, Wvl, ba, bv, out);

        dim3 sg(B_SZ * D_SZ / 64, NCHUNK);
        scan_part<<<sg, 64, 0, stream>>>(out, P, Q);
        scan_comb<<<B_SZ * D_SZ / 64, 64, 0, stream>>>(out, P, Q, S);
        scan_final<<<sg, 64, 0, stream>>>(out, S);
    } else {
        dim3 grid(M_SZ / BM, N_SZ / BN);
        gemm_gates_fb<<<grid, 256, 0, stream>>>(x, Wa, ba, Wv, bv, out);
        scan_hier<<<(B_SZ * D_SZ) / SC_LANES, 1024, 0, stream>>>(out);
    }
}

// Round 10
// 603.755 us; speedup vs baseline: 1.4618x; 1.4618x over previous
//
#include <hip/hip_runtime.h>
#include <hip/hip_bf16.h>
#include <math.h>

#define T_STEPS 2048
#define B_SZ 8
#define D_SZ 1024
#define M_SZ (T_STEPS * B_SZ)   // 16384 rows (t*B + b)
#define K_SZ D_SZ               // 1024
#define N_SZ (2 * D_SZ)         // 2048 (alpha cols | v cols)

#define BM 128
#define BN 128
#define BK 32

typedef __attribute__((ext_vector_type(8))) short bf16x8;
typedef __attribute__((ext_vector_type(4))) float f32x4;

__device__ __forceinline__ float sigmoidf_(float z) {
    return 1.0f / (1.0f + __expf(-z));
}

// round-to-nearest-even fp32 -> bf16, also returns the back-converted fp32
__device__ __forceinline__ ushort bf16_rne(float f, float* back) {
    uint u = __float_as_uint(f);
    uint r = (u + 0x7FFFu + ((u >> 16) & 1u)) >> 16;
    *back = __uint_as_float(r << 16);
    return (ushort)r;
}

// ---------------- conversion pre-pass: fp32 -> (hi, lo) bf16 arrays ----------
__global__ __launch_bounds__(256) void conv_split(
    const float* __restrict__ src,
    ushort* __restrict__ dh,
    ushort* __restrict__ dl,
    int n8)
{
    const int i = blockIdx.x * 256 + threadIdx.x;
    if (i >= n8) return;
    const size_t base = (size_t)i * 8;
    const float4 f0 = *reinterpret_cast<const float4*>(src + base);
    const float4 f1 = *reinterpret_cast<const float4*>(src + base + 4);
    const float f[8] = {f0.x, f0.y, f0.z, f0.w, f1.x, f1.y, f1.z, f1.w};
    ushort hi[8], lo[8];
    #pragma unroll
    for (int j = 0; j < 8; ++j) {
        float back;
        hi[j] = bf16_rne(f[j], &back);
        float dummy;
        lo[j] = bf16_rne(f[j] - back, &dummy);
    }
    *reinterpret_cast<uint4*>(dh + base) = *reinterpret_cast<const uint4*>(hi);
    *reinterpret_cast<uint4*>(dl + base) = *reinterpret_cast<const uint4*>(lo);
}

// ---------------- hybrid GEMM: A = x (fused hi/lo convert), B = pre-split W --
// LDS row = 64 ushort = 128 B = 8 chunks of 16 B. Chunks 0-3: hi k=0..31,
// chunks 4-7: lo k=0..31. Physical chunk = logical ^ (row & 7) (bijective,
// conflict-free b128 reads — verified round 9, conflicts = 0).
__global__ __launch_bounds__(256) void gemm_gates3(
    const float* __restrict__ x,
    const ushort* __restrict__ Wah, const ushort* __restrict__ Wal,
    const ushort* __restrict__ Wvh, const ushort* __restrict__ Wvl,
    const float* __restrict__ ba, const float* __restrict__ bv,
    float* __restrict__ out)
{
    __shared__ ushort sA[BM * 64];
    __shared__ ushort sB[BN * 64];

    const int m0 = blockIdx.x * BM;
    const int n0 = blockIdx.y * BN;
    const bool is_v = (n0 >= D_SZ);
    const int n0l = is_v ? (n0 - D_SZ) : n0;
    const ushort* Bh = (is_v ? Wvh : Wah) + (size_t)n0l * K_SZ;
    const ushort* Bl = (is_v ? Wvl : Wal) + (size_t)n0l * K_SZ;

    const int tid = threadIdx.x;
    const int wid = tid >> 6;
    const int lane = tid & 63;
    const int wm = wid >> 1;
    const int wn = wid & 1;
    const int l15 = lane & 15;
    const int l4 = lane >> 4;

    // A staging (x fp32, fused convert): rows r0+32p, k-span c4*4..c4*4+3
    const int r0 = tid >> 3;     // 0..31
    const int c4 = tid & 7;      // 0..7
    const float* xp = x + (size_t)(m0 + r0) * K_SZ + c4 * 4;
    const int chA = c4 >> 1;           // 16B chunk (0..3) within hi region
    const int half = (c4 & 1) * 4;     // ushort offset within chunk

    // B staging (pre-split): lanes c4<4 load hi chunk c4, c4>=4 lo chunk c4-4
    const ushort* Bsrc = (c4 < 4) ? Bh : Bl;
    const int kcB = (c4 & 3) * 8;

    f32x4 acc[4][4];
    #pragma unroll
    for (int i = 0; i < 4; ++i)
        #pragma unroll
        for (int j = 0; j < 4; ++j)
            acc[i][j] = (f32x4){0.f, 0.f, 0.f, 0.f};

    for (int k0 = 0; k0 < K_SZ; k0 += BK) {
        float4 av[4];
        uint4 bw[4];
        #pragma unroll
        for (int p = 0; p < 4; ++p) {
            av[p] = *reinterpret_cast<const float4*>(xp + k0 + (size_t)(32 * p) * K_SZ);
            bw[p] = *reinterpret_cast<const uint4*>(
                Bsrc + (size_t)(r0 + 32 * p) * K_SZ + k0 + kcB);
        }

        __syncthreads();   // previous iteration's LDS reads complete

        #pragma unroll
        for (int p = 0; p < 4; ++p) {
            const int row = r0 + 32 * p;
            // A: convert 4 floats -> hi/lo, write 8B each into swizzled chunks
            float bk;
            ushort4 hi, lo;
            const float fa[4] = {av[p].x, av[p].y, av[p].z, av[p].w};
            hi.x = bf16_rne(fa[0], &bk); lo.x = bf16_rne(fa[0] - bk, &bk);
            hi.y = bf16_rne(fa[1], &bk); lo.y = bf16_rne(fa[1] - bk, &bk);
            hi.z = bf16_rne(fa[2], &bk); lo.z = bf16_rne(fa[2] - bk, &bk);
            hi.w = bf16_rne(fa[3], &bk); lo.w = bf16_rne(fa[3] - bk, &bk);
            const int phH = (chA) ^ (row & 7);
            const int phL = (chA + 4) ^ (row & 7);
            *reinterpret_cast<ushort4*>(&sA[row * 64 + phH * 8 + half]) = hi;
            *reinterpret_cast<ushort4*>(&sA[row * 64 + phL * 8 + half]) = lo;
            // B: direct 16B store, swizzled
            const int phB = c4 ^ (row & 7);
            *reinterpret_cast<uint4*>(&sB[row * 64 + phB * 8]) = bw[p];
        }

        __syncthreads();

        bf16x8 ah[4], al[4];
        #pragma unroll
        for (int i = 0; i < 4; ++i) {
            const int r = wm * 64 + i * 16 + l15;
            const int ph = (l4) ^ (r & 7);
            const int pl = (4 + l4) ^ (r & 7);
            ah[i] = *reinterpret_cast<const bf16x8*>(&sA[r * 64 + ph * 8]);
            al[i] = *reinterpret_cast<const bf16x8*>(&sA[r * 64 + pl * 8]);
        }
        #pragma unroll
        for (int j = 0; j < 4; ++j) {
            const int cr = wn * 64 + j * 16 + l15;
            const int ph = (l4) ^ (cr & 7);
            const int pl = (4 + l4) ^ (cr & 7);
            const bf16x8 bh = *reinterpret_cast<const bf16x8*>(&sB[cr * 64 + ph * 8]);
            const bf16x8 bl = *reinterpret_cast<const bf16x8*>(&sB[cr * 64 + pl * 8]);
            #pragma unroll
            for (int i = 0; i < 4; ++i) {
                acc[i][j] = __builtin_amdgcn_mfma_f32_16x16x32_bf16(ah[i], bh, acc[i][j], 0, 0, 0);
                acc[i][j] = __builtin_amdgcn_mfma_f32_16x16x32_bf16(al[i], bh, acc[i][j], 0, 0, 0);
                acc[i][j] = __builtin_amdgcn_mfma_f32_16x16x32_bf16(ah[i], bl, acc[i][j], 0, 0, 0);
            }
        }
    }

    float* hbuf = out + (size_t)M_SZ * D_SZ;
    #pragma unroll
    for (int j = 0; j < 4; ++j) {
        const int n = n0 + wn * 64 + j * 16 + l15;
        const float bb = is_v ? bv[n - D_SZ] : ba[n];
        #pragma unroll
        for (int i = 0; i < 4; ++i) {
            const int mb = m0 + wm * 64 + i * 16 + l4 * 4;
            #pragma unroll
            for (int r = 0; r < 4; ++r) {
                const int m = mb + r;
                const float z = acc[i][j][r] + bb;
                if (!is_v) {
                    out[(size_t)m * D_SZ + n] = sigmoidf_(z);
                } else {
                    hbuf[(size_t)(m + B_SZ) * D_SZ + (n - D_SZ)] = z;
                }
            }
        }
    }
}

// ---------------- 3-kernel coalesced scan -----------------------------------
#define NCHUNK 64
#define CLEN (T_STEPS / NCHUNK)   // 32
#define STRIDE (B_SZ * D_SZ)      // 8192

__global__ __launch_bounds__(64) void scan_part(
    const float* __restrict__ out, float* __restrict__ P, float* __restrict__ Q)
{
    const int bd = blockIdx.x * 64 + threadIdx.x;
    const int chunk = blockIdx.y;
    const float* alpha = out;
    const float* hbuf = out + (size_t)M_SZ * D_SZ;

    float Pa = 1.f, q = 0.f;
    size_t idx = (size_t)(chunk * CLEN) * STRIDE + bd;
    #pragma unroll 4
    for (int s = 0; s < CLEN; ++s) {
        const float a = alpha[idx];
        const float v = hbuf[idx + STRIDE];
        q = fmaf(a, q, v);
        Pa *= a;
        idx += STRIDE;
    }
    P[(size_t)chunk * STRIDE + bd] = Pa;
    Q[(size_t)chunk * STRIDE + bd] = q;
}

__global__ __launch_bounds__(64) void scan_comb(
    float* __restrict__ out, const float* __restrict__ P,
    const float* __restrict__ Q, float* __restrict__ S)
{
    const int bd = blockIdx.x * 64 + threadIdx.x;
    float* hbuf = out + (size_t)M_SZ * D_SZ;
    float s = 0.f;
    #pragma unroll 8
    for (int c = 0; c < NCHUNK; ++c) {
        S[(size_t)c * STRIDE + bd] = s;
        s = fmaf(P[(size_t)c * STRIDE + bd], s, Q[(size_t)c * STRIDE + bd]);
    }
    hbuf[bd] = 0.f;   // h0
}

__global__ __launch_bounds__(64) void scan_final(
    float* __restrict__ out, const float* __restrict__ S)
{
    const int bd = blockIdx.x * 64 + threadIdx.x;
    const int chunk = blockIdx.y;
    float* alpha = out;
    float* hbuf = out + (size_t)M_SZ * D_SZ;

    float h = S[(size_t)chunk * STRIDE + bd];
    size_t idx = (size_t)(chunk * CLEN) * STRIDE + bd;
    #pragma unroll 4
    for (int s = 0; s < CLEN; ++s) {
        const float a = alpha[idx];
        const float v = hbuf[idx + STRIDE];
        h = fmaf(a, h, v);
        hbuf[idx + STRIDE] = h;
        alpha[idx] = h * h * sigmoidf_(h);
        idx += STRIDE;
    }
}

// ---------------- fallback (round-5) kernels --------------------------------
#define LDSS 40
__global__ __launch_bounds__(256) void gemm_gates_fb(
    const float* __restrict__ x,
    const float* __restrict__ Wa,
    const float* __restrict__ ba,
    const float* __restrict__ Wv,
    const float* __restrict__ bv,
    float* __restrict__ out)
{
    __shared__ ushort sAh[BM * LDSS];
    __shared__ ushort sAl[BM * LDSS];
    __shared__ ushort sBh[BN * LDSS];
    __shared__ ushort sBl[BN * LDSS];

    const int m0 = blockIdx.x * BM;
    const int n0 = blockIdx.y * BN;
    const bool is_v = (n0 >= D_SZ);
    const float* W = is_v ? (Wv + (size_t)(n0 - D_SZ) * K_SZ) : (Wa + (size_t)n0 * K_SZ);

    const int tid = threadIdx.x;
    const int wid = tid >> 6;
    const int lane = tid & 63;
    const int wm = wid >> 1;
    const int wn = wid & 1;
    const int l15 = lane & 15;
    const int l4 = lane >> 4;
    const int r0 = tid >> 3;
    const int c4 = tid & 7;

    const float* xp = x + (size_t)(m0 + r0) * K_SZ + c4 * 4;
    const float* wp = W + (size_t)r0 * K_SZ + c4 * 4;

    f32x4 acc[4][4];
    #pragma unroll
    for (int i = 0; i < 4; ++i)
        #pragma unroll
        for (int j = 0; j < 4; ++j)
            acc[i][j] = (f32x4){0.f, 0.f, 0.f, 0.f};

    for (int k0 = 0; k0 < K_SZ; k0 += BK) {
        float4 areg[4], breg[4];
        #pragma unroll
        for (int p = 0; p < 4; ++p) {
            areg[p] = *reinterpret_cast<const float4*>(xp + k0 + (size_t)(32 * p) * K_SZ);
            breg[p] = *reinterpret_cast<const float4*>(wp + k0 + (size_t)(32 * p) * K_SZ);
        }
        __syncthreads();
        #pragma unroll
        for (int p = 0; p < 4; ++p) {
            const int e = (r0 + 32 * p) * LDSS + c4 * 4;
            float bk;
            ushort4 hi, lo;
            float fa[4] = {areg[p].x, areg[p].y, areg[p].z, areg[p].w};
            hi.x = bf16_rne(fa[0], &bk); lo.x = bf16_rne(fa[0] - bk, &bk);
            hi.y = bf16_rne(fa[1], &bk); lo.y = bf16_rne(fa[1] - bk, &bk);
            hi.z = bf16_rne(fa[2], &bk); lo.z = bf16_rne(fa[2] - bk, &bk);
            hi.w = bf16_rne(fa[3], &bk); lo.w = bf16_rne(fa[3] - bk, &bk);
            *reinterpret_cast<ushort4*>(&sAh[e]) = hi;
            *reinterpret_cast<ushort4*>(&sAl[e]) = lo;
            float fb[4] = {breg[p].x, breg[p].y, breg[p].z, breg[p].w};
            hi.x = bf16_rne(fb[0], &bk); lo.x = bf16_rne(fb[0] - bk, &bk);
            hi.y = bf16_rne(fb[1], &bk); lo.y = bf16_rne(fb[1] - bk, &bk);
            hi.z = bf16_rne(fb[2], &bk); lo.z = bf16_rne(fb[2] - bk, &bk);
            hi.w = bf16_rne(fb[3], &bk); lo.w = bf16_rne(fb[3] - bk, &bk);
            *reinterpret_cast<ushort4*>(&sBh[e]) = hi;
            *reinterpret_cast<ushort4*>(&sBl[e]) = lo;
        }
        __syncthreads();

        bf16x8 ah[4], al[4];
        #pragma unroll
        for (int i = 0; i < 4; ++i) {
            const int r = wm * 64 + i * 16 + l15;
            ah[i] = *reinterpret_cast<const bf16x8*>(&sAh[r * LDSS + l4 * 8]);
            al[i] = *reinterpret_cast<const bf16x8*>(&sAl[r * LDSS + l4 * 8]);
        }
        #pragma unroll
        for (int j = 0; j < 4; ++j) {
            const int c = wn * 64 + j * 16 + l15;
            const bf16x8 bh = *reinterpret_cast<const bf16x8*>(&sBh[c * LDSS + l4 * 8]);
            const bf16x8 bl = *reinterpret_cast<const bf16x8*>(&sBl[c * LDSS + l4 * 8]);
            #pragma unroll
            for (int i = 0; i < 4; ++i) {
                acc[i][j] = __builtin_amdgcn_mfma_f32_16x16x32_bf16(ah[i], bh, acc[i][j], 0, 0, 0);
                acc[i][j] = __builtin_amdgcn_mfma_f32_16x16x32_bf16(al[i], bh, acc[i][j], 0, 0, 0);
                acc[i][j] = __builtin_amdgcn_mfma_f32_16x16x32_bf16(ah[i], bl, acc[i][j], 0, 0, 0);
            }
        }
    }

    float* hbuf = out + (size_t)M_SZ * D_SZ;
    #pragma unroll
    for (int j = 0; j < 4; ++j) {
        const int n = n0 + wn * 64 + j * 16 + l15;
        const float bb = is_v ? bv[n - D_SZ] : ba[n];
        #pragma unroll
        for (int i = 0; i < 4; ++i) {
            const int mb = m0 + wm * 64 + i * 16 + l4 * 4;
            #pragma unroll
            for (int r = 0; r < 4; ++r) {
                const int m = mb + r;
                const float z = acc[i][j][r] + bb;
                if (!is_v) {
                    out[(size_t)m * D_SZ + n] = sigmoidf_(z);
                } else {
                    hbuf[(size_t)(m + B_SZ) * D_SZ + (n - D_SZ)] = z;
                }
            }
        }
    }
}

#define SC_LANES 16
#define SC_CHUNKS 64
#define SC_LEN (T_STEPS / SC_CHUNKS)

__global__ __launch_bounds__(1024) void scan_hier(float* __restrict__ out)
{
    __shared__ float sP[SC_CHUNKS][SC_LANES];
    __shared__ float sQ[SC_CHUNKS][SC_LANES];
    __shared__ float sS[SC_CHUNKS][SC_LANES];

    float* alpha = out;
    float* hbuf = out + (size_t)M_SZ * D_SZ;
    const int tid = threadIdx.x;
    const int c = tid >> 4;
    const int l = tid & 15;
    const int bd = blockIdx.x * SC_LANES + l;
    const int t0 = c * SC_LEN;

    float P = 1.f, q = 0.f;
    {
        size_t idx = (size_t)t0 * STRIDE + bd;
        #pragma unroll 4
        for (int s = 0; s < SC_LEN; ++s) {
            const float a = alpha[idx];
            const float v = hbuf[idx + STRIDE];
            q = fmaf(a, q, v);
            P *= a;
            idx += STRIDE;
        }
    }
    sP[c][l] = P;
    sQ[c][l] = q;
    __syncthreads();

    if (tid < SC_LANES) {
        float s = 0.f;
        #pragma unroll 8
        for (int w = 0; w < SC_CHUNKS; ++w) {
            sS[w][tid] = s;
            s = fmaf(sP[w][tid], s, sQ[w][tid]);
        }
        hbuf[blockIdx.x * SC_LANES + tid] = 0.f;
    }
    __syncthreads();

    float h = sS[c][l];
    {
        size_t idx = (size_t)t0 * STRIDE + bd;
        #pragma unroll 4
        for (int s = 0; s < SC_LEN; ++s) {
            const float a = alpha[idx];
            const float v = hbuf[idx + STRIDE];
            h = fmaf(a, h, v);
            hbuf[idx + STRIDE] = h;
            alpha[idx] = h * h * sigmoidf_(h);
            idx += STRIDE;
        }
    }
}

// ---------------- launch ----------------------------------------------------
extern "C" void kernel_launch(void* const* d_in, const int* in_sizes, int n_in,
                              void* d_out, int out_size, void* d_ws, size_t ws_size,
                              hipStream_t stream) {
    const float* x  = (const float*)d_in[0];
    const float* Wa = (const float*)d_in[1];
    const float* ba = (const float*)d_in[2];
    const float* Wv = (const float*)d_in[3];
    const float* bv = (const float*)d_in[4];
    float* out = (float*)d_out;

    const size_t MB = 1024 * 1024;

    if (ws_size >= 16 * MB) {
        char* ws = (char*)d_ws;
        ushort* Wah = (ushort*)(ws);
        ushort* Wal = (ushort*)(ws + 2 * MB);
        ushort* Wvh = (ushort*)(ws + 4 * MB);
        ushort* Wvl = (ushort*)(ws + 6 * MB);
        float* P = (float*)(ws + 8 * MB);
        float* Q = (float*)(ws + 10 * MB);
        float* S = (float*)(ws + 12 * MB);

        conv_split<<<(D_SZ * K_SZ / 8 + 255) / 256, 256, 0, stream>>>(Wa, Wah, Wal, D_SZ * K_SZ / 8);
        conv_split<<<(D_SZ * K_SZ / 8 + 255) / 256, 256, 0, stream>>>(Wv, Wvh, Wvl, D_SZ * K_SZ / 8);

        dim3 grid(M_SZ / BM, N_SZ / BN);
        gemm_gates3<<<grid, 256, 0, stream>>>(x, Wah, Wal, Wvh, Wvl, ba, bv, out);

        dim3 sg(B_SZ * D_SZ / 64, NCHUNK);
        scan_part<<<sg, 64, 0, stream>>>(out, P, Q);
        scan_comb<<<B_SZ * D_SZ / 64, 64, 0, stream>>>(out, P, Q, S);
        scan_final<<<sg, 64, 0, stream>>>(out, S);
    } else {
        dim3 grid(M_SZ / BM, N_SZ / BN);
        gemm_gates_fb<<<grid, 256, 0, stream>>>(x, Wa, ba, Wv, bv, out);
        scan_hier<<<(B_SZ * D_SZ) / SC_LANES, 1024, 0, stream>>>(out);
    }
}